// Round 1
// baseline (282.163 us; speedup 1.0000x reference)
//
#include <hip/hip_runtime.h>
#include <hip/hip_bf16.h>

#define B_ 64
#define N_ 4096
#define F_ 512
#define D_ 256
#define BM 64
#define BK 64

typedef __attribute__((ext_vector_type(8))) short short8;
typedef __attribute__((ext_vector_type(4))) float f32x4;

__device__ __forceinline__ unsigned short f2bf(float f) {
  unsigned int u = __float_as_uint(f);
  u += 0x7FFFu + ((u >> 16) & 1u);   // RNE round to bf16
  return (unsigned short)(u >> 16);
}

__device__ __forceinline__ float fast_tanh(float x) {
  float e = __expf(-2.0f * fabsf(x));
  float t = (1.0f - e) / (1.0f + e);
  return copysignf(t, x);
}

// ---- prep: W_img f32 [256][512] -> bf16 chunked [kt][256][64] for global_load_lds
__global__ void prep_w_kernel(const float* __restrict__ Wimg,
                              unsigned short* __restrict__ wbf) {
  int d = blockIdx.x;        // 0..255
  int f = threadIdx.x;       // 0..511
  float v = Wimg[d * F_ + f];
  int kt = f >> 6, fp = f & 63;
  wbf[kt * (D_ * BK) + d * BK + fp] = f2bf(v);
}

// ---- prep: proj_hidden[b][d] = sum_h hidden[b][h] * W_hid[d][h]  (f32)
__global__ void prep_ph_kernel(const float* __restrict__ hid,
                               const float* __restrict__ Whid,
                               float* __restrict__ ph) {
  int b = blockIdx.x, d = threadIdx.x;  // 64 x 256
  const float4* hv = (const float4*)(hid + b * F_);   // H == 512
  const float4* wv = (const float4*)(Whid + d * F_);
  float acc = 0.f;
#pragma unroll 4
  for (int i = 0; i < 128; i++) {
    float4 h = hv[i], w = wv[i];
    acc += h.x * w.x + h.y * w.y + h.z * w.z + h.w * w.w;
  }
  ph[b * D_ + d] = acc;
}

// ---- main: scores[b][n] = sum_d tanh(feat[b,n,:]·W_img[d,:] + ph[b,d]) * wscore[d]
// Tile: 64 rows (n) x 256 cols (full D). 4 waves, each 64x64 via 4x4 frags of 16x16x32.
__global__ __launch_bounds__(256, 3) void scores_kernel(
    const float* __restrict__ feat, const unsigned short* __restrict__ wbf,
    const float* __restrict__ ph, const float* __restrict__ wscore,
    float* __restrict__ scores) {
  __shared__ unsigned short Ab[BM * BK];   // 8 KiB, row-major [row][k]
  __shared__ unsigned short Bb[D_ * BK];   // 32 KiB, row-major [d][k]
  __shared__ float red[BM][4];             // 1 KiB

  int tid = threadIdx.x;
  int lane = tid & 63, wn = tid >> 6;      // wave = d-group 0..3
  int lr = lane & 15, lg = lane >> 4;

  int blk = blockIdx.x;                    // 4096 blocks
  int b = blk >> 6, chunk = blk & 63;
  int n0 = chunk * BM;

  const float* arow = feat + (size_t)(b * N_ + n0) * F_;

  f32x4 acc[4][4];
#pragma unroll
  for (int m = 0; m < 4; m++)
#pragma unroll
    for (int n = 0; n < 4; n++) acc[m][n] = (f32x4)0.f;

  for (int kt = 0; kt < F_ / BK; kt++) {
    __syncthreads();
    // stage B: 32 KiB bf16 via global_load_lds (pre-chunked layout)
    {
      const char* src = (const char*)(wbf + kt * (D_ * BK));
#pragma unroll
      for (int i = 0; i < 8; i++) {
        int off = tid * 16 + i * 4096;
        __builtin_amdgcn_global_load_lds(
            (const __attribute__((address_space(1))) void*)(src + off),
            (__attribute__((address_space(3))) void*)((char*)Bb + off),
            16, 0, 0);
      }
    }
    // stage A: 64 rows x 64 f32 -> bf16 (reg-staged, coalesced float4)
#pragma unroll
    for (int i = 0; i < 4; i++) {
      int idx4 = tid + i * 256;            // float4 index in 64x64 tile
      int r = idx4 >> 4, c4 = idx4 & 15;
      float4 v = *(const float4*)(arow + (size_t)r * F_ + kt * BK + c4 * 4);
      unsigned int p0 = (unsigned)f2bf(v.x) | ((unsigned)f2bf(v.y) << 16);
      unsigned int p1 = (unsigned)f2bf(v.z) | ((unsigned)f2bf(v.w) << 16);
      *(uint2*)(Ab + r * BK + c4 * 4) = make_uint2(p0, p1);
    }
    __syncthreads();
    // compute: 2 k-slices of 32
#pragma unroll
    for (int ks = 0; ks < 2; ks++) {
      short8 af[4], bfr[4];
#pragma unroll
      for (int m = 0; m < 4; m++)
        af[m] = *(const short8*)(Ab + (m * 16 + lr) * BK + ks * 32 + lg * 8);
#pragma unroll
      for (int n = 0; n < 4; n++)
        bfr[n] = *(const short8*)(Bb + (wn * 64 + n * 16 + lr) * BK + ks * 32 + lg * 8);
#pragma unroll
      for (int m = 0; m < 4; m++)
#pragma unroll
        for (int n = 0; n < 4; n++)
          acc[m][n] = __builtin_amdgcn_mfma_f32_16x16x32_bf16(af[m], bfr[n], acc[m][n], 0, 0, 0);
    }
  }

  // epilogue: score[row] = sum_d tanh(proj + ph) * wscore
  float ph4[4], wv4[4];
#pragma unroll
  for (int n = 0; n < 4; n++) {
    int d = wn * 64 + n * 16 + lr;
    ph4[n] = ph[b * D_ + d];
    wv4[n] = wscore[d];
  }
#pragma unroll
  for (int m = 0; m < 4; m++) {
#pragma unroll
    for (int j = 0; j < 4; j++) {
      float p = 0.f;
#pragma unroll
      for (int n = 0; n < 4; n++)
        p += fast_tanh(acc[m][n][j] + ph4[n]) * wv4[n];
      p += __shfl_xor(p, 1);
      p += __shfl_xor(p, 2);
      p += __shfl_xor(p, 4);
      p += __shfl_xor(p, 8);
      if (lr == 0) red[m * 16 + lg * 4 + j][wn] = p;
    }
  }
  __syncthreads();
  if (tid < BM) {
    float s = red[tid][0] + red[tid][1] + red[tid][2] + red[tid][3];
    scores[b * N_ + n0 + tid] = s;
  }
}

// ---- softmax over N per batch
__global__ void softmax_kernel(const float* __restrict__ scores,
                               float* __restrict__ wout) {
  __shared__ float lm[16], lsum[16];
  int b = blockIdx.x, tid = threadIdx.x;  // 1024 threads
  int lane = tid & 63, wid = tid >> 6;
  float s[4];
#pragma unroll
  for (int k = 0; k < 4; k++) s[k] = scores[b * N_ + tid + k * 1024];
  float m = fmaxf(fmaxf(s[0], s[1]), fmaxf(s[2], s[3]));
#pragma unroll
  for (int o = 1; o < 64; o <<= 1) m = fmaxf(m, __shfl_xor(m, o));
  if (lane == 0) lm[wid] = m;
  __syncthreads();
  float M = lm[0];
#pragma unroll
  for (int i = 1; i < 16; i++) M = fmaxf(M, lm[i]);
  float e[4], ls = 0.f;
#pragma unroll
  for (int k = 0; k < 4; k++) { e[k] = __expf(s[k] - M); ls += e[k]; }
#pragma unroll
  for (int o = 1; o < 64; o <<= 1) ls += __shfl_xor(ls, o);
  if (lane == 0) lsum[wid] = ls;
  __syncthreads();
  float Z = 0.f;
#pragma unroll
  for (int i = 0; i < 16; i++) Z += lsum[i];
  float inv = 1.0f / Z;
#pragma unroll
  for (int k = 0; k < 4; k++) wout[b * N_ + tid + k * 1024] = e[k] * inv;
}

// ---- context partials: part[blk][f] = sum over 128 rows of w*feat
__global__ void ctx_partial_kernel(const float* __restrict__ feat,
                                   const float* __restrict__ wts,
                                   float* __restrict__ part) {
  int blk = blockIdx.x;            // 2048 = 64 b x 32 chunks of 128 rows
  int b = blk >> 5, chunk = blk & 31;
  int n0 = chunk * 128;
  int t = threadIdx.x;             // 256 threads, 2 cols each (float2)
  const float* base = feat + (size_t)(b * N_ + n0) * F_;
  const float* wb = wts + b * N_ + n0;
  float ax = 0.f, ay = 0.f;
#pragma unroll 4
  for (int r = 0; r < 128; r++) {
    float w = wb[r];
    float2 v = *(const float2*)(base + (size_t)r * F_ + t * 2);
    ax += w * v.x; ay += w * v.y;
  }
  float2 o; o.x = ax; o.y = ay;
  *(float2*)(part + (size_t)blk * F_ + t * 2) = o;
}

// ---- combine partials
__global__ void ctx_combine_kernel(const float* __restrict__ part,
                                   float* __restrict__ ctx) {
  int b = blockIdx.x, f = threadIdx.x;  // 64 x 512
  float s = 0.f;
#pragma unroll
  for (int c = 0; c < 32; c++) s += part[(size_t)(b * 32 + c) * F_ + f];
  ctx[b * F_ + f] = s;
}

extern "C" void kernel_launch(void* const* d_in, const int* in_sizes, int n_in,
                              void* d_out, int out_size, void* d_ws, size_t ws_size,
                              hipStream_t stream) {
  const float* feat   = (const float*)d_in[0];   // [64,4096,512]
  const float* hid    = (const float*)d_in[1];   // [64,512]
  const float* Wimg   = (const float*)d_in[2];   // [256,512]
  const float* Whid   = (const float*)d_in[3];   // [256,512]
  const float* Wscore = (const float*)d_in[4];   // [1,256]

  float* ctx  = (float*)d_out;            // [64,512]
  float* wout = (float*)d_out + B_ * F_;  // [64,4096]

  // workspace layout
  unsigned short* wbf = (unsigned short*)d_ws;                       // 256 KiB
  float* ph     = (float*)((char*)d_ws + 262144);                    // 64 KiB
  float* scores = (float*)((char*)d_ws + 262144 + 65536);            // 1 MiB
  float* part   = (float*)((char*)d_ws + 262144 + 65536 + 1048576);  // 4 MiB

  prep_w_kernel<<<D_, F_, 0, stream>>>(Wimg, wbf);
  prep_ph_kernel<<<B_, D_, 0, stream>>>(hid, Whid, ph);
  scores_kernel<<<(B_ * N_) / BM, 256, 0, stream>>>(feat, wbf, ph, Wscore, scores);
  softmax_kernel<<<B_, 1024, 0, stream>>>(scores, wout);
  ctx_partial_kernel<<<B_ * 32, 256, 0, stream>>>(feat, wout, part);
  ctx_combine_kernel<<<B_, F_, 0, stream>>>(part, ctx);
}

// Round 2
// 241.323 us; speedup vs baseline: 1.1692x; 1.1692x over previous
//
#include <hip/hip_runtime.h>
#include <hip/hip_bf16.h>

#define B_ 64
#define N_ 4096
#define F_ 512
#define D_ 256
#define BM 64
#define BK 64
#define APAD 520   // halves per LDS row (1040 B -> bank stride 4, 2-way = free)

typedef __attribute__((ext_vector_type(8))) short short8;
typedef __attribute__((ext_vector_type(4))) float f32x4;

__device__ __forceinline__ unsigned short f2bf(float f) {
  unsigned int u = __float_as_uint(f);
  u += 0x7FFFu + ((u >> 16) & 1u);   // RNE round to bf16
  return (unsigned short)(u >> 16);
}

__device__ __forceinline__ float fast_tanh(float x) {
  float e = __expf(-2.0f * fabsf(x));
  float t = (1.0f - e) / (1.0f + e);
  return copysignf(t, x);
}

// ---- prep: W_img f32 [256][512] -> bf16 in exact MFMA B-fragment order.
// Frag block (kt,ks,d16): 64 lanes x 16B. lane = lg*16+lr holds
// B[d = d16*16+lr][k = kt*64+ks*32+lg*8 + e], e=0..7.
__global__ void prep_w_kernel(const float* __restrict__ Wimg,
                              unsigned short* __restrict__ wfrag) {
  int d = blockIdx.x;        // 0..255
  int f = threadIdx.x;       // 0..511
  int kt = f >> 6, ks = (f >> 5) & 1, lg = (f >> 3) & 3, e = f & 7;
  int lr = d & 15, d16 = d >> 4;
  int lane = lg * 16 + lr;
  int idx = (((kt * 2 + ks) * 16 + d16) * 64 + lane) * 8 + e;
  wfrag[idx] = f2bf(Wimg[d * F_ + f]);
}

// ---- prep: proj_hidden[b][d] = sum_h hidden[b][h] * W_hid[d][h]  (f32)
__global__ void prep_ph_kernel(const float* __restrict__ hid,
                               const float* __restrict__ Whid,
                               float* __restrict__ ph) {
  int b = blockIdx.x, d = threadIdx.x;  // 64 x 256
  const float4* hv = (const float4*)(hid + b * F_);   // H == 512
  const float4* wv = (const float4*)(Whid + d * F_);
  float acc = 0.f;
#pragma unroll 4
  for (int i = 0; i < 128; i++) {
    float4 h = hv[i], w = wv[i];
    acc += h.x * w.x + h.y * w.y + h.z * w.z + h.w * w.w;
  }
  ph[b * D_ + d] = acc;
}

// ---- fused: GEMM(feat x W^T) + tanh + score + block-local softmax partial
//      + context partial from the LDS-resident bf16 feat tile.
__global__ __launch_bounds__(256, 2) void fused_kernel(
    const float* __restrict__ feat, const unsigned short* __restrict__ wfrag,
    const float* __restrict__ ph, const float* __restrict__ wscore,
    float* __restrict__ expw, float2* __restrict__ meta,
    float* __restrict__ part) {
  __shared__ unsigned short Afull[BM * APAD];  // 65 KiB bf16 feat tile
  __shared__ float red[BM][4];
  __shared__ float sbuf[BM];
  __shared__ float ewf[BM];

  int tid = threadIdx.x;
  int lane = tid & 63, wn = tid >> 6;
  int lr = lane & 15, lg = lane >> 4;

  int blk = blockIdx.x;                    // 4096 blocks
  int b = blk >> 6, chunk = blk & 63;
  int n0 = chunk * BM;

  const float* arow = feat + (size_t)(b * N_ + n0) * F_;

  f32x4 acc[4][4];
#pragma unroll
  for (int m = 0; m < 4; m++)
#pragma unroll
    for (int n = 0; n < 4; n++) acc[m][n] = (f32x4)0.f;

  int r_[4], c4_[4];
#pragma unroll
  for (int i = 0; i < 4; i++) {
    int idx4 = tid + i * 256;
    r_[i] = idx4 >> 4;
    c4_[i] = idx4 & 15;
  }

  // prologue: stage kt=0
  float4 av[4];
#pragma unroll
  for (int i = 0; i < 4; i++)
    av[i] = *(const float4*)(arow + (size_t)r_[i] * F_ + c4_[i] * 4);
#pragma unroll
  for (int i = 0; i < 4; i++) {
    unsigned int p0 = (unsigned)f2bf(av[i].x) | ((unsigned)f2bf(av[i].y) << 16);
    unsigned int p1 = (unsigned)f2bf(av[i].z) | ((unsigned)f2bf(av[i].w) << 16);
    *(uint2*)(Afull + r_[i] * APAD + c4_[i] * 4) = make_uint2(p0, p1);
  }
  __syncthreads();

  for (int kt = 0; kt < F_ / BK; kt++) {
    if (kt < 7) {
#pragma unroll
      for (int i = 0; i < 4; i++)
        av[i] = *(const float4*)(arow + (size_t)r_[i] * F_ + (kt + 1) * BK + c4_[i] * 4);
    }
    short8 bfr[2][4], af[2][4];
#pragma unroll
    for (int ks = 0; ks < 2; ks++)
#pragma unroll
      for (int n = 0; n < 4; n++)
        bfr[ks][n] = *(const short8*)(wfrag +
            (size_t)(((kt * 2 + ks) * 16 + wn * 4 + n) * 64 + lane) * 8);
#pragma unroll
    for (int ks = 0; ks < 2; ks++)
#pragma unroll
      for (int m = 0; m < 4; m++)
        af[ks][m] = *(const short8*)(Afull + (m * 16 + lr) * APAD + kt * BK + ks * 32 + lg * 8);
#pragma unroll
    for (int ks = 0; ks < 2; ks++)
#pragma unroll
      for (int m = 0; m < 4; m++)
#pragma unroll
        for (int n = 0; n < 4; n++)
          acc[m][n] = __builtin_amdgcn_mfma_f32_16x16x32_bf16(af[ks][m], bfr[ks][n], acc[m][n], 0, 0, 0);
    if (kt < 7) {
#pragma unroll
      for (int i = 0; i < 4; i++) {
        unsigned int p0 = (unsigned)f2bf(av[i].x) | ((unsigned)f2bf(av[i].y) << 16);
        unsigned int p1 = (unsigned)f2bf(av[i].z) | ((unsigned)f2bf(av[i].w) << 16);
        *(uint2*)(Afull + r_[i] * APAD + (kt + 1) * BK + c4_[i] * 4) = make_uint2(p0, p1);
      }
    }
    __syncthreads();
  }

  // ---- scores: s[row] = sum_d tanh(proj + ph) * wscore
  float ph4[4], wv4[4];
#pragma unroll
  for (int n = 0; n < 4; n++) {
    int d = wn * 64 + n * 16 + lr;
    ph4[n] = ph[b * D_ + d];
    wv4[n] = wscore[d];
  }
#pragma unroll
  for (int m = 0; m < 4; m++) {
#pragma unroll
    for (int j = 0; j < 4; j++) {
      float p = 0.f;
#pragma unroll
      for (int n = 0; n < 4; n++)
        p += fast_tanh(acc[m][n][j] + ph4[n]) * wv4[n];
      p += __shfl_xor(p, 1);
      p += __shfl_xor(p, 2);
      p += __shfl_xor(p, 4);
      p += __shfl_xor(p, 8);
      if (lr == 0) red[m * 16 + lg * 4 + j][wn] = p;
    }
  }
  __syncthreads();
  if (tid < BM) sbuf[tid] = red[tid][0] + red[tid][1] + red[tid][2] + red[tid][3];
  __syncthreads();

  // block-local softmax partials
  float mb = -1e30f;
#pragma unroll
  for (int r = 0; r < BM; r++) mb = fmaxf(mb, sbuf[r]);
  if (tid < BM) {
    float e = __expf(sbuf[tid] - mb);
    ewf[tid] = e;
    expw[b * N_ + n0 + tid] = e;
    float l = e;
#pragma unroll
    for (int o = 1; o < 64; o <<= 1) l += __shfl_xor(l, o);
    if (tid == 0) meta[blk] = make_float2(mb, l);
  }
  __syncthreads();

  // ---- context partial from LDS bf16 tile: part[blk][f] = sum_r e_r * feat[r][f]
  int f0 = tid * 2;
  float a0 = 0.f, a1 = 0.f;
#pragma unroll 8
  for (int r = 0; r < BM; r++) {
    float w = ewf[r];
    unsigned int v = *(const unsigned int*)(Afull + r * APAD + f0);
    a0 += w * __uint_as_float(v << 16);
    a1 += w * __uint_as_float(v & 0xffff0000u);
  }
  float2 o; o.x = a0; o.y = a1;
  *(float2*)(part + (size_t)blk * F_ + f0) = o;
}

// ---- finalize per batch: global softmax merge + context combine + weights
__global__ void finalize_kernel(const float* __restrict__ part,
                                const float2* __restrict__ meta,
                                const float* __restrict__ expw,
                                float* __restrict__ ctx,
                                float* __restrict__ wout) {
  __shared__ float sm[64], sl[64], se[64];
  int b = blockIdx.x, t = threadIdx.x;   // 512 threads
  if (t < 64) {
    float2 ml = meta[b * 64 + t];
    sm[t] = ml.x;
    sl[t] = ml.y;
  }
  __syncthreads();
  float M = -1e30f;
#pragma unroll
  for (int i = 0; i < 64; i++) M = fmaxf(M, sm[i]);
  float Z = 0.f;
#pragma unroll
  for (int i = 0; i < 64; i++) Z += sl[i] * __expf(sm[i] - M);
  if (t < 64) se[t] = __expf(sm[t] - M);
  __syncthreads();
  float invZ = 1.0f / Z;
  // context: thread t owns col t
  float acc = 0.f;
#pragma unroll 8
  for (int i = 0; i < 64; i++) acc += part[(size_t)(b * 64 + i) * F_ + t] * se[i];
  ctx[b * F_ + t] = acc * invZ;
  // weights
#pragma unroll
  for (int k = 0; k < 8; k++) {
    int n = k * 512 + t;
    wout[b * N_ + n] = expw[b * N_ + n] * se[n >> 6] * invZ;
  }
}

extern "C" void kernel_launch(void* const* d_in, const int* in_sizes, int n_in,
                              void* d_out, int out_size, void* d_ws, size_t ws_size,
                              hipStream_t stream) {
  const float* feat   = (const float*)d_in[0];   // [64,4096,512]
  const float* hid    = (const float*)d_in[1];   // [64,512]
  const float* Wimg   = (const float*)d_in[2];   // [256,512]
  const float* Whid   = (const float*)d_in[3];   // [256,512]
  const float* Wscore = (const float*)d_in[4];   // [1,256]

  float* ctx  = (float*)d_out;            // [64,512]
  float* wout = (float*)d_out + B_ * F_;  // [64,4096]

  // workspace layout
  unsigned short* wfrag = (unsigned short*)d_ws;                         // 256 KiB
  float*  ph    = (float*)((char*)d_ws + 262144);                        // 64 KiB
  float*  expw  = (float*)((char*)d_ws + 327680);                        // 1 MiB
  float2* meta  = (float2*)((char*)d_ws + 1376256);                      // 32 KiB
  float*  part  = (float*)((char*)d_ws + 1409024);                       // 8 MiB

  prep_w_kernel<<<D_, F_, 0, stream>>>(Wimg, wfrag);
  prep_ph_kernel<<<B_, D_, 0, stream>>>(hid, Whid, ph);
  fused_kernel<<<(B_ * N_) / BM, 256, 0, stream>>>(feat, wfrag, ph, Wscore, expw, meta, part);
  finalize_kernel<<<B_, 512, 0, stream>>>(part, meta, expw, ctx, wout);
}

// Round 3
// 212.842 us; speedup vs baseline: 1.3257x; 1.1338x over previous
//
#include <hip/hip_runtime.h>
#include <hip/hip_bf16.h>

#define B_ 64
#define N_ 4096
#define F_ 512
#define D_ 256
#define BM 32
#define BK 64
#define APAD 520                 // halves per LDS row (1040 B)
#define NCHUNK (N_ / BM)         // 128 chunks per batch
#define NBLK (B_ * NCHUNK)       // 8192 blocks

typedef __attribute__((ext_vector_type(8))) short short8;
typedef __attribute__((ext_vector_type(4))) float f32x4;

__device__ __forceinline__ unsigned short f2bf(float f) {
  unsigned int u = __float_as_uint(f);
  u += 0x7FFFu + ((u >> 16) & 1u);   // RNE round to bf16
  return (unsigned short)(u >> 16);
}

__device__ __forceinline__ unsigned int pk2bf(float x, float y) {
  float2 f; f.x = x; f.y = y;
  __hip_bfloat162 h = __float22bfloat162_rn(f);   // v_cvt_pk_bf16_f32
  union { __hip_bfloat162 h2; unsigned int u; } cv; cv.h2 = h;
  return cv.u;                                    // x in low 16 bits
}

__device__ __forceinline__ float fast_tanh(float x) {
  float e = __expf(-2.0f * fabsf(x));
  float t = (1.0f - e) / (1.0f + e);
  return copysignf(t, x);
}

// ---- prep: W_img f32 [256][512] -> bf16 in exact MFMA B-fragment order.
__global__ void prep_w_kernel(const float* __restrict__ Wimg,
                              unsigned short* __restrict__ wfrag) {
  int d = blockIdx.x;        // 0..255
  int f = threadIdx.x;       // 0..511
  int kt = f >> 6, ks = (f >> 5) & 1, lg = (f >> 3) & 3, e = f & 7;
  int lr = d & 15, d16 = d >> 4;
  int lane = lg * 16 + lr;
  int idx = (((kt * 2 + ks) * 16 + d16) * 64 + lane) * 8 + e;
  wfrag[idx] = f2bf(Wimg[d * F_ + f]);
}

// ---- prep: proj_hidden[b][d]
__global__ void prep_ph_kernel(const float* __restrict__ hid,
                               const float* __restrict__ Whid,
                               float* __restrict__ ph) {
  int b = blockIdx.x, d = threadIdx.x;  // 64 x 256
  const float4* hv = (const float4*)(hid + b * F_);
  const float4* wv = (const float4*)(Whid + d * F_);
  float acc = 0.f;
#pragma unroll 4
  for (int i = 0; i < 128; i++) {
    float4 h = hv[i], w = wv[i];
    acc += h.x * w.x + h.y * w.y + h.z * w.z + h.w * w.w;
  }
  ph[b * D_ + d] = acc;
}

// ---- fused: GEMM + tanh + score + block softmax partial + ctx partial
__global__ __launch_bounds__(256, 4) void fused_kernel(
    const float* __restrict__ feat, const unsigned short* __restrict__ wfrag,
    const float* __restrict__ ph, const float* __restrict__ wscore,
    float* __restrict__ expw, float2* __restrict__ meta,
    float* __restrict__ part) {
  __shared__ unsigned short Afull[BM * APAD];  // 33.3 KiB bf16 feat tile
  __shared__ float red[BM][4];
  __shared__ float sbuf[BM];
  __shared__ float ewf[BM];

  int tid = threadIdx.x;
  int lane = tid & 63, wn = tid >> 6;
  int lr = lane & 15, lg = lane >> 4;

  int blk = blockIdx.x;                    // 8192
  int b = blk >> 7, chunk = blk & 127;
  int n0 = chunk * BM;

  const float* arow = feat + (size_t)(b * N_ + n0) * F_;

  f32x4 acc[2][4];
#pragma unroll
  for (int m = 0; m < 2; m++)
#pragma unroll
    for (int n = 0; n < 4; n++) acc[m][n] = (f32x4)0.f;

  int r_[2], c4_[2];
#pragma unroll
  for (int i = 0; i < 2; i++) {
    int idx4 = tid + i * 256;   // float4 index within 32x64 slice
    r_[i] = idx4 >> 4;
    c4_[i] = idx4 & 15;
  }

#define LOADA(buf, kt_)                                                        \
  _Pragma("unroll") for (int i = 0; i < 2; i++)                                \
      buf[i] = *(const float4*)(arow + (size_t)r_[i] * F_ + (kt_)*BK + c4_[i] * 4);

#define CVTWRITE(buf, kt_)                                                     \
  _Pragma("unroll") for (int i = 0; i < 2; i++) {                              \
    unsigned int p0 = pk2bf(buf[i].x, buf[i].y);                               \
    unsigned int p1 = pk2bf(buf[i].z, buf[i].w);                               \
    *(uint2*)(Afull + r_[i] * APAD + (kt_)*BK + c4_[i] * 4) = make_uint2(p0, p1); \
  }

#define MFMASTEP(kt_)                                                          \
  _Pragma("unroll") for (int ks = 0; ks < 2; ks++) {                           \
    short8 bfr[4], af[2];                                                      \
    _Pragma("unroll") for (int n = 0; n < 4; n++)                              \
        bfr[n] = *(const short8*)(wfrag +                                      \
            (size_t)((((kt_)*2 + ks) * 16 + wn * 4 + n) * 64 + lane) * 8);     \
    _Pragma("unroll") for (int m = 0; m < 2; m++)                              \
        af[m] = *(const short8*)(Afull + (m * 16 + lr) * APAD + (kt_)*BK + ks * 32 + lg * 8); \
    _Pragma("unroll") for (int m = 0; m < 2; m++)                              \
      _Pragma("unroll") for (int n = 0; n < 4; n++)                            \
        acc[m][n] = __builtin_amdgcn_mfma_f32_16x16x32_bf16(af[m], bfr[n], acc[m][n], 0, 0, 0); \
  }

  float4 rA[2], rB[2];
  // prologue: 2-deep
  LOADA(rA, 0);
  LOADA(rB, 1);
  CVTWRITE(rA, 0);
  __syncthreads();

#pragma unroll
  for (int kt = 0; kt < 8; kt += 2) {
    // even half: compute kt; rB holds kt+1 (in flight since last iter)
    if (kt + 2 < 8) { LOADA(rA, kt + 2); }
    MFMASTEP(kt);
    CVTWRITE(rB, kt + 1);
    __syncthreads();
    // odd half: compute kt+1; rA holds kt+2
    if (kt + 3 < 8) { LOADA(rB, kt + 3); }
    MFMASTEP(kt + 1);
    if (kt + 2 < 8) { CVTWRITE(rA, kt + 2); }
    __syncthreads();
  }

  // ---- scores: s[row] = sum_d tanh(proj + ph) * wscore
  float ph4[4], wv4[4];
#pragma unroll
  for (int n = 0; n < 4; n++) {
    int d = wn * 64 + n * 16 + lr;
    ph4[n] = ph[b * D_ + d];
    wv4[n] = wscore[d];
  }
#pragma unroll
  for (int m = 0; m < 2; m++) {
#pragma unroll
    for (int j = 0; j < 4; j++) {
      float p = 0.f;
#pragma unroll
      for (int n = 0; n < 4; n++)
        p += fast_tanh(acc[m][n][j] + ph4[n]) * wv4[n];
      p += __shfl_xor(p, 1);
      p += __shfl_xor(p, 2);
      p += __shfl_xor(p, 4);
      p += __shfl_xor(p, 8);
      if (lr == 0) red[m * 16 + lg * 4 + j][wn] = p;
    }
  }
  __syncthreads();
  if (tid < BM) sbuf[tid] = red[tid][0] + red[tid][1] + red[tid][2] + red[tid][3];
  __syncthreads();

  // block-local softmax partials
  float mb = -1e30f;
#pragma unroll
  for (int r = 0; r < BM; r++) mb = fmaxf(mb, sbuf[r]);
  if (tid < BM) {
    float e = __expf(sbuf[tid] - mb);
    ewf[tid] = e;
    expw[b * N_ + n0 + tid] = e;
    float l = e;
#pragma unroll
    for (int o = 1; o < 32; o <<= 1) l += __shfl_xor(l, o);
    if (tid == 0) meta[blk] = make_float2(mb, l);
  }
  __syncthreads();

  // ---- context partial from LDS bf16 tile
  int f0 = tid * 2;
  float a0 = 0.f, a1 = 0.f;
#pragma unroll 8
  for (int r = 0; r < BM; r++) {
    float w = ewf[r];
    unsigned int v = *(const unsigned int*)(Afull + r * APAD + f0);
    a0 += w * __uint_as_float(v << 16);
    a1 += w * __uint_as_float(v & 0xffff0000u);
  }
  float2 o; o.x = a0; o.y = a1;
  *(float2*)(part + (size_t)blk * F_ + f0) = o;
}

// ---- finalize per batch: global softmax merge + context combine + weights
__global__ void finalize_kernel(const float* __restrict__ part,
                                const float2* __restrict__ meta,
                                const float* __restrict__ expw,
                                float* __restrict__ ctx,
                                float* __restrict__ wout) {
  __shared__ float sm[NCHUNK], sl[NCHUNK], se[NCHUNK];
  int b = blockIdx.x, t = threadIdx.x;   // 512 threads
  if (t < NCHUNK) {
    float2 ml = meta[b * NCHUNK + t];
    sm[t] = ml.x;
    sl[t] = ml.y;
  }
  __syncthreads();
  float M = -1e30f;
#pragma unroll 8
  for (int i = 0; i < NCHUNK; i++) M = fmaxf(M, sm[i]);
  float Z = 0.f;
#pragma unroll 8
  for (int i = 0; i < NCHUNK; i++) Z += sl[i] * __expf(sm[i] - M);
  if (t < NCHUNK) se[t] = __expf(sm[t] - M);
  __syncthreads();
  float invZ = 1.0f / Z;
  // context: thread t owns col t
  float acc = 0.f;
#pragma unroll 8
  for (int i = 0; i < NCHUNK; i++) acc += part[(size_t)(b * NCHUNK + i) * F_ + t] * se[i];
  ctx[b * F_ + t] = acc * invZ;
  // weights
#pragma unroll
  for (int k = 0; k < 8; k++) {
    int n = k * 512 + t;
    wout[b * N_ + n] = expw[b * N_ + n] * se[n >> 5] * invZ;
  }
}

extern "C" void kernel_launch(void* const* d_in, const int* in_sizes, int n_in,
                              void* d_out, int out_size, void* d_ws, size_t ws_size,
                              hipStream_t stream) {
  const float* feat   = (const float*)d_in[0];   // [64,4096,512]
  const float* hid    = (const float*)d_in[1];   // [64,512]
  const float* Wimg   = (const float*)d_in[2];   // [256,512]
  const float* Whid   = (const float*)d_in[3];   // [256,512]
  const float* Wscore = (const float*)d_in[4];   // [1,256]

  float* ctx  = (float*)d_out;            // [64,512]
  float* wout = (float*)d_out + B_ * F_;  // [64,4096]

  // workspace layout
  unsigned short* wfrag = (unsigned short*)d_ws;                 // 256 KiB
  float*  ph    = (float*)((char*)d_ws + 262144);                // 64 KiB
  float*  expw  = (float*)((char*)d_ws + 327680);                // 1 MiB
  float2* meta  = (float2*)((char*)d_ws + 1376256);              // 64 KiB
  float*  part  = (float*)((char*)d_ws + 1441792);               // 16 MiB

  prep_w_kernel<<<D_, F_, 0, stream>>>(Wimg, wfrag);
  prep_ph_kernel<<<B_, D_, 0, stream>>>(hid, Whid, ph);
  fused_kernel<<<NBLK, 256, 0, stream>>>(feat, wfrag, ph, Wscore, expw, meta, part);
  finalize_kernel<<<B_, 512, 0, stream>>>(part, meta, expw, ctx, wout);
}